// Round 21
// baseline (132.183 us; speedup 1.0000x reference)
//
#include <hip/hip_runtime.h>
#include <hip/hip_bf16.h>
#include <math.h>

#define NH 16
#define DH 64
#define SEQ 2048
#define EMBED 1024
#define DINNER 1024
#define BATCH 2
#define MTOK 4096   // BATCH*SEQ

typedef __bf16 bf16x8 __attribute__((ext_vector_type(8)));
typedef float  f32x4  __attribute__((ext_vector_type(4)));
typedef float  f32x16 __attribute__((ext_vector_type(16)));
typedef unsigned int u32;

// async global->LDS, 16B per lane (dest = wave-uniform base + lane*16)
__device__ __forceinline__ void gload16(const void* g, void* l) {
    __builtin_amdgcn_global_load_lds((const __attribute__((address_space(1))) void*)g,
                                     (__attribute__((address_space(3))) void*)l, 16, 0, 0);
}

// ---------------------------------------------------------------------------
// f32 -> bf16 flat convert (n divisible by 4)
// ---------------------------------------------------------------------------
__global__ __launch_bounds__(256) void cvt_bf16(
    const float* __restrict__ src, __bf16* __restrict__ dst, int n)
{
    int i = (blockIdx.x * 256 + threadIdx.x) * 4;
    if (i + 3 < n) {
        float4 v = *(const float4*)&src[i];
        dst[i + 0] = (__bf16)v.x;
        dst[i + 1] = (__bf16)v.y;
        dst[i + 2] = (__bf16)v.z;
        dst[i + 3] = (__bf16)v.w;
    }
}

// ---------------------------------------------------------------------------
// 4 weight transposes (all 1024x1024) in one launch: src[R][C] f32 -> dst[C][R] bf16
// ---------------------------------------------------------------------------
__global__ __launch_bounds__(256) void tconv4(
    const float* __restrict__ W0, const float* __restrict__ W1,
    const float* __restrict__ W2, const float* __restrict__ W3,
    __bf16* __restrict__ D0, __bf16* __restrict__ D1,
    __bf16* __restrict__ D2, __bf16* __restrict__ D3)
{
    const int z = blockIdx.z;
    const float* __restrict__ src = (z == 0) ? W0 : (z == 1) ? W1 : (z == 2) ? W2 : W3;
    __bf16* __restrict__ dst      = (z == 0) ? D0 : (z == 1) ? D1 : (z == 2) ? D2 : D3;
    const int R = 1024, C = 1024;

    __shared__ float t[32][33];
    const int c0 = blockIdx.x * 32, r0 = blockIdx.y * 32;
    const int x = threadIdx.x & 31, y = threadIdx.x >> 5;   // 32 x 8
#pragma unroll
    for (int i = 0; i < 4; ++i)
        t[y + 8 * i][x] = src[(size_t)(r0 + y + 8 * i) * C + c0 + x];
    __syncthreads();
#pragma unroll
    for (int i = 0; i < 4; ++i)
        dst[(size_t)(c0 + y + 8 * i) * R + r0 + x] = (__bf16)t[x][y + 8 * i];
}

// ---------------------------------------------------------------------------
// bf16 MFMA GEMM, 128x128 tile, EIGHT waves (4 m x 2 n), wave-tile 32x64,
// 16x16x32 MFMA, K-step 32. m97 recipe: linear LDS via global_load_lds w=16.
// (r20-validated: 8 waves/block -> out-proj 2 waves/SIMD; total -11 us.)
// A[M][K] bf16, Bt[N][K] bf16 (pre-transposed weights).
// mode3=0: blockIdx.z selects Q/K/V epilogue; mode3=1: fp32 out[m][EMBED]+bias.
//   z=0 -> Q layout [bh][s][d] bf16, scaled by 0.125*log2e (exp2-domain softmax)
//   z=1 -> K layout [bh][s][d] bf16
//   z=2 -> V layout transposed [bh][d][s] bf16 (uint2 store along s)
// ---------------------------------------------------------------------------
#define QSCALE 0.18033688f   // 0.125 * log2(e)

__global__ __launch_bounds__(512) void gemm128(
    const __bf16* __restrict__ A,
    const __bf16* __restrict__ Bt0, const __bf16* __restrict__ Bt1, const __bf16* __restrict__ Bt2,
    const float* __restrict__ b0, const float* __restrict__ b1, const float* __restrict__ b2,
    void* __restrict__ o0, void* __restrict__ o1, void* __restrict__ o2,
    int Kdim, int mode3)
{
    const int z = blockIdx.z;
    const __bf16* __restrict__ Bt = (z == 0) ? Bt0 : (z == 1) ? Bt1 : Bt2;
    const float*  __restrict__ bias = (z == 0) ? b0 : (z == 1) ? b1 : b2;
    void* __restrict__ outp = (z == 0) ? o0 : (z == 1) ? o1 : o2;
    const int mode = mode3 ? 3 : z;

    __shared__ __bf16 As[128 * 32];   // 8 KB
    __shared__ __bf16 Bs[128 * 32];   // 8 KB

    const int tid  = threadIdx.x;     // 0..511
    const int lane = tid & 63;
    const int wid  = tid >> 6;        // 0..7
    const int wm = wid >> 1, wn = wid & 1;   // 4 x 2 wave grid
    const int ls = lane & 15, lg = lane >> 4;
    const int m0 = blockIdx.y * 128, n0 = blockIdx.x * 128;

    const int sr = tid >> 2;           // 0..127 (one row per 4 threads)
    const int sc = (tid & 3) * 8;      // element col offset (8 bf16 = 16B)

    f32x4 acc[2][4] = {};

    for (int k0 = 0; k0 < Kdim; k0 += 32) {
        gload16(&A [(size_t)(m0 + sr) * Kdim + k0 + sc], &As[sr * 32 + sc]);
        gload16(&Bt[(size_t)(n0 + sr) * Kdim + k0 + sc], &Bs[sr * 32 + sc]);
        __syncthreads();

        bf16x8 af[2], bfr[4];
#pragma unroll
        for (int i = 0; i < 2; ++i)
            af[i] = *(const bf16x8*)&As[(wm * 32 + i * 16 + ls) * 32 + lg * 8];
#pragma unroll
        for (int jx = 0; jx < 4; ++jx)
            bfr[jx] = *(const bf16x8*)&Bs[(wn * 64 + jx * 16 + ls) * 32 + lg * 8];
#pragma unroll
        for (int i = 0; i < 2; ++i)
#pragma unroll
            for (int jx = 0; jx < 4; ++jx)
                acc[i][jx] = __builtin_amdgcn_mfma_f32_16x16x32_bf16(af[i], bfr[jx], acc[i][jx], 0, 0, 0);
        __syncthreads();
    }

    // epilogue: C/D layout col = lane&15, row = (lane>>4)*4 + j   [m89-verified]
#pragma unroll
    for (int i = 0; i < 2; ++i) {
#pragma unroll
        for (int jx = 0; jx < 4; ++jx) {
            const int mbase = m0 + wm * 32 + i * 16 + lg * 4;
            const int n = n0 + wn * 64 + jx * 16 + ls;
            if (mode == 3) {
#pragma unroll
                for (int j = 0; j < 4; ++j)
                    ((float*)outp)[(size_t)(mbase + j) * EMBED + n] = acc[i][jx][j] + bias[n];
            } else if (mode == 2) {
                // V^T [bh][d][s]: j-loop contiguous along s -> one 8B store
                const int b = mbase >> 11, s = mbase & 2047;
                const int h = n >> 6, d = n & 63;
                __bf16 t4[4];
#pragma unroll
                for (int j = 0; j < 4; ++j) t4[j] = (__bf16)(acc[i][jx][j] + bias[n]);
                *(uint2*)&((__bf16*)outp)[(((size_t)(b * NH + h) * DH + d) << 11) + s] = *(uint2*)t4;
            } else {
                const float sc2 = (mode == 0) ? QSCALE : 1.0f;
#pragma unroll
                for (int j = 0; j < 4; ++j) {
                    const int m = mbase + j;
                    const int b = m >> 11, s = m & 2047;
                    const int h = n >> 6, d = n & 63;
                    ((__bf16*)outp)[((((size_t)(b * NH + h) << 11) + s) * DH) + d] =
                        (__bf16)((acc[i][jx][j] + bias[n]) * sc2);
                }
            }
        }
    }
}

// ---------------------------------------------------------------------------
// MFMA causal flash attention — round-16 skeleton + DUAL-ISSUE DOUBLE BUFFER.
// r21 theory: per-tile cost ~4500 cyc = ~1800 busy + ~2700 exposed vmcnt
// stalls (K_{t+1} waited ~1200 cyc after issue; V_t similar). Fix: issue
// K_{t+1} AND V_{t+1} together right after QK^T's fence, into buf (t+1)&1
// (its old contents were consumed at tile t-1 and lgkm-fenced at loop end).
// Wait distances become: K_t wait covers softmax+PV of t-1; V_t wait covers
// ~a full tile. LDS = 32 KB (2 x (K 8KB | V 8KB)) — r5/r6/r15 showed 32 KB
// runs at the same ~12% occupancy as 16 KB, avoiding r17's 48KB trap.
// vmcnt: K-wait (8) [V_t younger]; V-wait (16) [V_t + K/V_{t+1} = 24 out] or
// (0) on the final tile. One wave per block, frozen-max softmax, swapped
// QK^T (S^T=K@Q^T), P->bf16 via v_cvt_pk_bf16_f32 + v_permlane32_swap_b32,
// XOR-swizzled LDS rows (pre-swizzled global source per rule #21).
// Grid = 32 bh x 64 q-tiles = 2048 blocks x 64 thr, heavy-first; same-bh
// blocks stride 32 -> same XCD.
// Q,K: [bh][s][d] bf16 (Q pre-scaled 0.125*log2e). Vt: [bh][d][s] bf16.
// ctx: bf16 [b*SEQ+s][h*64+d].
// ---------------------------------------------------------------------------
__global__ __launch_bounds__(64) void attn_mfma(
    const __bf16* __restrict__ Q, const __bf16* __restrict__ K,
    const __bf16* __restrict__ Vt, __bf16* __restrict__ ctx)
{
    __shared__ __bf16 lds[2][8192];      // per buf: [0,8192)=K tile, [8192,16384)=V^T

    const int lane = threadIdx.x & 63;
    const int col  = lane & 31;          // q column / fragment row index
    const int hi   = lane >> 5;
    const int bh   = blockIdx.x & 31;    // same-bh blocks stride 32 -> same XCD
    const int qt32 = 63 - (blockIdx.x >> 5);  // reversed: long blocks first
    const int qlo  = qt32 * 32;          // this block's 32 q rows
    const int b = bh >> 4, h = bh & 15;

    const __bf16* __restrict__ Qb = Q + ((size_t)bh << 11) * DH;
    const char* __restrict__ Kg = (const char*)(K  + ((size_t)bh << 11) * DH);
    const char* __restrict__ Vg = (const char*)(Vt + ((size_t)bh << 11) * DH);

    // staging (64 lanes): instr i covers tile bytes [i*1024 + lane*16);
    // row = i*8 + (lane>>3); col-byte = (lane&7)*16; row&7 = lane>>3
    const int srow = lane >> 3;                              // 0..7
    const int sswz = ((lane & 7) * 16) ^ (srow << 4);        // pre-swizzled source col
    const int swz  = (col & 7) << 4;

    // Q B-frags (col = q, k-dim = d)
    bf16x8 qf[4];
#pragma unroll
    for (int c = 0; c < 4; ++c)
        qf[c] = *(const bf16x8*)&Qb[(size_t)(qlo + col) * DH + c * 16 + hi * 8];

    const int nt = (qt32 + 2) >> 1;      // 64-key tiles covering keys 0..qlo+31

    // prologue: stage tile 0 into buf 0 (K then V; 16 loads in flight)
#pragma unroll
    for (int i = 0; i < 8; ++i)
        gload16(Kg + (size_t)(i * 8 + srow) * 128 + sswz,
                (char*)&lds[0][0] + i * 1024 + lane * 16);
#pragma unroll
    for (int i = 0; i < 8; ++i)
        gload16(Vg + (size_t)(i * 8 + srow) * 4096 + sswz,
                (char*)&lds[0][0] + 8192 + i * 1024 + lane * 16);

    f32x16 oT0 = {}, oT1 = {};           // O^T[d][q], d-halves 0-31 / 32-63
    float mrun = 0.f, lrun = 0.f;        // mrun set on tile 0, then FROZEN

    for (int t = 0; t < nt; ++t) {
        const int k0 = t * 64;
        const char* ldsK = (const char*)&lds[t & 1][0];
        const char* ldsV = ldsK + 8192;
        const bool more = (t + 1 < nt);

        // ---- K_t ready (V_t still in flight) ----
        asm volatile("s_waitcnt vmcnt(8)" ::: "memory");

        // ---- K fragments for both 32-key subtiles (swizzled LDS read) ----
        bf16x8 kfa[4], kfb[4];
#pragma unroll
        for (int c = 0; c < 4; ++c) {
            kfa[c] = *(const bf16x8*)(ldsK + (     col) * 128 + ((c * 32 + hi * 16) ^ swz));
            kfb[c] = *(const bf16x8*)(ldsK + (32 + col) * 128 + ((c * 32 + hi * 16) ^ swz));
        }

        // ---- QK^T: two independent S^T[32k][32q] chains ----
        __builtin_amdgcn_s_setprio(1);
        f32x16 sta = {}, stb = {};
#pragma unroll
        for (int c = 0; c < 4; ++c) {
            sta = __builtin_amdgcn_mfma_f32_32x32x16_bf16(kfa[c], qf[c], sta, 0, 0, 0);
            stb = __builtin_amdgcn_mfma_f32_32x32x16_bf16(kfb[c], qf[c], stb, 0, 0, 0);
        }
        __builtin_amdgcn_s_setprio(0);

        // ---- dual-issue K_{t+1} AND V_{t+1} into buf (t+1)&1 ----
        // (target buf's data was consumed at t-1; protected by prior loop-end
        //  fence. Issuing both here gives V_{t+1} a full-tile wait distance.)
        asm volatile("s_waitcnt lgkmcnt(0)" ::: "memory");
        __builtin_amdgcn_sched_barrier(0);
        if (more) {
            const int kbn = (t + 1) * 64;
            char* nK = (char*)&lds[(t + 1) & 1][0];
#pragma unroll
            for (int i = 0; i < 8; ++i)
                gload16(Kg + (size_t)(kbn + i * 8 + srow) * 128 + sswz,
                        nK + i * 1024 + lane * 16);
#pragma unroll
            for (int i = 0; i < 8; ++i)
                gload16(Vg + (size_t)(i * 8 + srow) * 4096 + (size_t)kbn * 2 + sswz,
                        nK + 8192 + i * 1024 + lane * 16);
        }

        // ---- causal mask (diagonal-crossing tiles only) ----
        if (k0 + 63 > qlo) {
#pragma unroll
            for (int r = 0; r < 16; ++r) {
                const int krel = (r & 3) + 8 * (r >> 2) + 4 * hi;
                if (k0 + krel > qlo + col)      sta[r] = -INFINITY;
                if (k0 + 32 + krel > qlo + col) stb[r] = -INFINITY;
            }
        }

        // ---- frozen-max softmax: fmax tree ONLY on tile 0 ----
        if (t == 0) {
            float ta = fmaxf(fmaxf(fmaxf(sta[0], sta[1]), fmaxf(sta[2], sta[3])),
                             fmaxf(fmaxf(sta[4], sta[5]), fmaxf(sta[6], sta[7])));
            float tb = fmaxf(fmaxf(fmaxf(sta[8], sta[9]),  fmaxf(sta[10], sta[11])),
                             fmaxf(fmaxf(sta[12], sta[13]), fmaxf(sta[14], sta[15])));
            float tc = fmaxf(fmaxf(fmaxf(stb[0], stb[1]), fmaxf(stb[2], stb[3])),
                             fmaxf(fmaxf(stb[4], stb[5]), fmaxf(stb[6], stb[7])));
            float td = fmaxf(fmaxf(fmaxf(stb[8], stb[9]),  fmaxf(stb[10], stb[11])),
                             fmaxf(fmaxf(stb[12], stb[13]), fmaxf(stb[14], stb[15])));
            float tmax = fmaxf(fmaxf(ta, tb), fmaxf(tc, td));
            tmax = fmaxf(tmax, __shfl_xor(tmax, 32));
            mrun = tmax;                 // finite: every q-row has >=1 unmasked key
        }

        float pa[16], pb[16];
#pragma unroll
        for (int r = 0; r < 16; ++r) { pa[r] = exp2f(sta[r] - mrun); pb[r] = exp2f(stb[r] - mrun); }
        float psa = (((pa[0] + pa[1]) + (pa[2] + pa[3])) + ((pa[4] + pa[5]) + (pa[6] + pa[7])))
                  + (((pa[8] + pa[9]) + (pa[10] + pa[11])) + ((pa[12] + pa[13]) + (pa[14] + pa[15])));
        float psb = (((pb[0] + pb[1]) + (pb[2] + pb[3])) + ((pb[4] + pb[5]) + (pb[6] + pb[7])))
                  + (((pb[8] + pb[9]) + (pb[10] + pb[11])) + ((pb[12] + pb[13]) + (pb[14] + pb[15])));
        float psum = psa + psb;
        psum += __shfl_xor(psum, 32);
        lrun += psum;

        // ---- pack P -> bf16 B-frags (cvt_pk + permlane32_swap), per subtile ----
        u32 wa[8], wb[8];
#pragma unroll
        for (int i = 0; i < 8; ++i) {
            u32 r1, r2;
            asm("v_cvt_pk_bf16_f32 %0, %1, %2" : "=v"(r1) : "v"(pa[2 * i]), "v"(pa[2 * i + 1]));
            asm("v_cvt_pk_bf16_f32 %0, %1, %2" : "=v"(r2) : "v"(pb[2 * i]), "v"(pb[2 * i + 1]));
            wa[i] = r1; wb[i] = r2;
        }
        asm("v_permlane32_swap_b32 %0, %1" : "+v"(wa[0]), "+v"(wa[2]));
        asm("v_permlane32_swap_b32 %0, %1" : "+v"(wa[1]), "+v"(wa[3]));
        asm("v_permlane32_swap_b32 %0, %1" : "+v"(wa[4]), "+v"(wa[6]));
        asm("v_permlane32_swap_b32 %0, %1" : "+v"(wa[5]), "+v"(wa[7]));
        asm("v_permlane32_swap_b32 %0, %1" : "+v"(wb[0]), "+v"(wb[2]));
        asm("v_permlane32_swap_b32 %0, %1" : "+v"(wb[1]), "+v"(wb[3]));
        asm("v_permlane32_swap_b32 %0, %1" : "+v"(wb[4]), "+v"(wb[6]));
        asm("v_permlane32_swap_b32 %0, %1" : "+v"(wb[5]), "+v"(wb[7]));

        union { u32 u4[4]; bf16x8 v; } cA0, cA1, cB0, cB1;
        cA0.u4[0] = wa[0]; cA0.u4[1] = wa[1]; cA0.u4[2] = wa[2]; cA0.u4[3] = wa[3];
        cA1.u4[0] = wa[4]; cA1.u4[1] = wa[5]; cA1.u4[2] = wa[6]; cA1.u4[3] = wa[7];
        cB0.u4[0] = wb[0]; cB0.u4[1] = wb[1]; cB0.u4[2] = wb[2]; cB0.u4[3] = wb[3];
        cB1.u4[0] = wb[4]; cB1.u4[1] = wb[5]; cB1.u4[2] = wb[6]; cB1.u4[3] = wb[7];

        // ---- V_t ready: outstanding = V_t + K_{t+1} + V_{t+1} (24) or V_t (8) ----
        if (more) { asm volatile("s_waitcnt vmcnt(16)" ::: "memory"); }
        else      { asm volatile("s_waitcnt vmcnt(0)" ::: "memory"); }

        // ---- PV from LDS V^T (swizzled read): O^T += V^T[d][k] P^T[k][q] ----
        __builtin_amdgcn_s_setprio(1);
#pragma unroll
        for (int dh = 0; dh < 2; ++dh) {
            bf16x8 v0 = *(const bf16x8*)(ldsV + (dh * 32 + col) * 128 + ((0  + hi * 16) ^ swz));
            bf16x8 v1 = *(const bf16x8*)(ldsV + (dh * 32 + col) * 128 + ((32 + hi * 16) ^ swz));
            bf16x8 v2 = *(const bf16x8*)(ldsV + (dh * 32 + col) * 128 + ((64 + hi * 16) ^ swz));
            bf16x8 v3 = *(const bf16x8*)(ldsV + (dh * 32 + col) * 128 + ((96 + hi * 16) ^ swz));
            f32x16& o = dh ? oT1 : oT0;
            o = __builtin_amdgcn_mfma_f32_32x32x16_bf16(v0, cA0.v, o, 0, 0, 0);
            o = __builtin_amdgcn_mfma_f32_32x32x16_bf16(v1, cA1.v, o, 0, 0, 0);
            o = __builtin_amdgcn_mfma_f32_32x32x16_bf16(v2, cB0.v, o, 0, 0, 0);
            o = __builtin_amdgcn_mfma_f32_32x32x16_bf16(v3, cB1.v, o, 0, 0, 0);
        }
        __builtin_amdgcn_s_setprio(0);

        // ---- fence V_t ds_reads: protects this buf for the issue at t+2 ----
        asm volatile("s_waitcnt lgkmcnt(0)" ::: "memory");
        __builtin_amdgcn_sched_barrier(0);
    }

    // ---- epilogue: O[q][d] = O^T/l -> ctx[token][h*64+d], 8B packed stores ----
    const float inv = 1.0f / lrun;
    const size_t base = ((size_t)(b * SEQ + qlo + col)) * DINNER + h * 64;
#pragma unroll
    for (int g = 0; g < 4; ++g) {
        __bf16 t4[4];
#pragma unroll
        for (int j = 0; j < 4; ++j) t4[j] = (__bf16)(oT0[4 * g + j] * inv);
        *(uint2*)&ctx[base + 8 * g + 4 * hi] = *(uint2*)t4;
#pragma unroll
        for (int j = 0; j < 4; ++j) t4[j] = (__bf16)(oT1[4 * g + j] * inv);
        *(uint2*)&ctx[base + 32 + 8 * g + 4 * hi] = *(uint2*)t4;
    }
}

// ---------------------------------------------------------------------------
extern "C" void kernel_launch(void* const* d_in, const int* in_sizes, int n_in,
                              void* d_out, int out_size, void* d_ws, size_t ws_size,
                              hipStream_t stream)
{
    const float* X  = (const float*)d_in[0];
    const float* Wq = (const float*)d_in[1];
    const float* bq = (const float*)d_in[2];
    const float* Wk = (const float*)d_in[3];
    const float* bk = (const float*)d_in[4];
    const float* Wv = (const float*)d_in[5];
    const float* bv = (const float*)d_in[6];
    const float* Wo = (const float*)d_in[7];
    const float* bo = (const float*)d_in[8];
    float* out = (float*)d_out;

    // bf16 workspace layout (element offsets, 1 Mi = 1048576)
    __bf16* ws  = (__bf16*)d_ws;
    const size_t MI = 1048576;
    __bf16* Xb   = ws;               // 4 Mi  [4096][1024]
    __bf16* Wtq  = ws + 4  * MI;     // 1 Mi  [1024 n][1024 k]
    __bf16* Wtk  = ws + 5  * MI;
    __bf16* Wtv  = ws + 6  * MI;
    __bf16* Wto  = ws + 7  * MI;
    __bf16* Qb   = ws + 8  * MI;     // 4 Mi  [bh][s][d], pre-scaled 0.125*log2e
    __bf16* Kb   = ws + 12 * MI;     // 4 Mi  [bh][s][d]
    __bf16* Vtb  = ws + 16 * MI;     // 4 Mi  [bh][d][s]
    __bf16* ctxb = ws + 20 * MI;     // 4 Mi  [tok][h*64+d]

    // 1) convert input + 4 weight transposes
    cvt_bf16<<<dim3(MTOK * EMBED / 1024), dim3(256), 0, stream>>>(X, Xb, MTOK * EMBED);
    tconv4<<<dim3(32, 32, 4), dim3(256), 0, stream>>>(Wq, Wk, Wv, Wo, Wtq, Wtk, Wtv, Wto);

    // 2) fused QKV projection: 128^2 tile, 8 waves -> 768 blocks x 512 thr
    {
        dim3 grid(DINNER / 128, MTOK / 128, 3), blk(512);
        gemm128<<<grid, blk, 0, stream>>>(Xb, Wtq, Wtk, Wtv, bq, bk, bv,
                                          Qb, Kb, Vtb, EMBED, 0);
    }

    // 3) causal flash attention (dual-issue double-buffer, frozen-max)
    {
        dim3 grid(32 * (SEQ / 32)), blk(64);
        attn_mfma<<<grid, blk, 0, stream>>>(Qb, Kb, Vtb, ctxb);
    }

    // 4) output projection -> fp32 d_out: 128^2 tile, 8 waves -> 256 blocks x 512 thr
    {
        dim3 grid(EMBED / 128, MTOK / 128, 1), blk(512);
        gemm128<<<grid, blk, 0, stream>>>(ctxb, Wto, Wto, Wto, bo, bo, bo,
                                          out, out, out, DINNER, 1);
    }
}

// Round 22
// 125.396 us; speedup vs baseline: 1.0541x; 1.0541x over previous
//
#include <hip/hip_runtime.h>
#include <hip/hip_bf16.h>
#include <math.h>

#define NH 16
#define DH 64
#define SEQ 2048
#define EMBED 1024
#define DINNER 1024
#define BATCH 2
#define MTOK 4096   // BATCH*SEQ

typedef __bf16 bf16x8 __attribute__((ext_vector_type(8)));
typedef float  f32x4  __attribute__((ext_vector_type(4)));
typedef float  f32x16 __attribute__((ext_vector_type(16)));
typedef unsigned int u32;

// async global->LDS, 16B per lane (dest = wave-uniform base + lane*16)
__device__ __forceinline__ void gload16(const void* g, void* l) {
    __builtin_amdgcn_global_load_lds((const __attribute__((address_space(1))) void*)g,
                                     (__attribute__((address_space(3))) void*)l, 16, 0, 0);
}

// ---------------------------------------------------------------------------
// f32 -> bf16 flat convert (n divisible by 4)
// ---------------------------------------------------------------------------
__global__ __launch_bounds__(256) void cvt_bf16(
    const float* __restrict__ src, __bf16* __restrict__ dst, int n)
{
    int i = (blockIdx.x * 256 + threadIdx.x) * 4;
    if (i + 3 < n) {
        float4 v = *(const float4*)&src[i];
        dst[i + 0] = (__bf16)v.x;
        dst[i + 1] = (__bf16)v.y;
        dst[i + 2] = (__bf16)v.z;
        dst[i + 3] = (__bf16)v.w;
    }
}

// ---------------------------------------------------------------------------
// 4 weight transposes (all 1024x1024) in one launch: src[R][C] f32 -> dst[C][R] bf16
// ---------------------------------------------------------------------------
__global__ __launch_bounds__(256) void tconv4(
    const float* __restrict__ W0, const float* __restrict__ W1,
    const float* __restrict__ W2, const float* __restrict__ W3,
    __bf16* __restrict__ D0, __bf16* __restrict__ D1,
    __bf16* __restrict__ D2, __bf16* __restrict__ D3)
{
    const int z = blockIdx.z;
    const float* __restrict__ src = (z == 0) ? W0 : (z == 1) ? W1 : (z == 2) ? W2 : W3;
    __bf16* __restrict__ dst      = (z == 0) ? D0 : (z == 1) ? D1 : (z == 2) ? D2 : D3;
    const int R = 1024, C = 1024;

    __shared__ float t[32][33];
    const int c0 = blockIdx.x * 32, r0 = blockIdx.y * 32;
    const int x = threadIdx.x & 31, y = threadIdx.x >> 5;   // 32 x 8
#pragma unroll
    for (int i = 0; i < 4; ++i)
        t[y + 8 * i][x] = src[(size_t)(r0 + y + 8 * i) * C + c0 + x];
    __syncthreads();
#pragma unroll
    for (int i = 0; i < 4; ++i)
        dst[(size_t)(c0 + y + 8 * i) * R + r0 + x] = (__bf16)t[x][y + 8 * i];
}

// ---------------------------------------------------------------------------
// bf16 MFMA GEMM, 128x128 tile, EIGHT waves (4 m x 2 n), wave-tile 32x64,
// 16x16x32 MFMA, K-step 32. m97 recipe: linear LDS via global_load_lds w=16.
// (r20-validated: 8 waves/block; total -11 us vs 4-wave.)
// A[M][K] bf16, Bt[N][K] bf16 (pre-transposed weights).
// mode3=0: blockIdx.z selects Q/K/V epilogue; mode3=1: fp32 out[m][EMBED]+bias.
// ---------------------------------------------------------------------------
#define QSCALE 0.18033688f   // 0.125 * log2(e)

__global__ __launch_bounds__(512) void gemm128(
    const __bf16* __restrict__ A,
    const __bf16* __restrict__ Bt0, const __bf16* __restrict__ Bt1, const __bf16* __restrict__ Bt2,
    const float* __restrict__ b0, const float* __restrict__ b1, const float* __restrict__ b2,
    void* __restrict__ o0, void* __restrict__ o1, void* __restrict__ o2,
    int Kdim, int mode3)
{
    const int z = blockIdx.z;
    const __bf16* __restrict__ Bt = (z == 0) ? Bt0 : (z == 1) ? Bt1 : Bt2;
    const float*  __restrict__ bias = (z == 0) ? b0 : (z == 1) ? b1 : b2;
    void* __restrict__ outp = (z == 0) ? o0 : (z == 1) ? o1 : o2;
    const int mode = mode3 ? 3 : z;

    __shared__ __bf16 As[128 * 32];   // 8 KB
    __shared__ __bf16 Bs[128 * 32];   // 8 KB

    const int tid  = threadIdx.x;     // 0..511
    const int lane = tid & 63;
    const int wid  = tid >> 6;        // 0..7
    const int wm = wid >> 1, wn = wid & 1;   // 4 x 2 wave grid
    const int ls = lane & 15, lg = lane >> 4;
    const int m0 = blockIdx.y * 128, n0 = blockIdx.x * 128;

    const int sr = tid >> 2;           // 0..127 (one row per 4 threads)
    const int sc = (tid & 3) * 8;      // element col offset (8 bf16 = 16B)

    f32x4 acc[2][4] = {};

    for (int k0 = 0; k0 < Kdim; k0 += 32) {
        gload16(&A [(size_t)(m0 + sr) * Kdim + k0 + sc], &As[sr * 32 + sc]);
        gload16(&Bt[(size_t)(n0 + sr) * Kdim + k0 + sc], &Bs[sr * 32 + sc]);
        __syncthreads();

        bf16x8 af[2], bfr[4];
#pragma unroll
        for (int i = 0; i < 2; ++i)
            af[i] = *(const bf16x8*)&As[(wm * 32 + i * 16 + ls) * 32 + lg * 8];
#pragma unroll
        for (int jx = 0; jx < 4; ++jx)
            bfr[jx] = *(const bf16x8*)&Bs[(wn * 64 + jx * 16 + ls) * 32 + lg * 8];
#pragma unroll
        for (int i = 0; i < 2; ++i)
#pragma unroll
            for (int jx = 0; jx < 4; ++jx)
                acc[i][jx] = __builtin_amdgcn_mfma_f32_16x16x32_bf16(af[i], bfr[jx], acc[i][jx], 0, 0, 0);
        __syncthreads();
    }

    // epilogue: C/D layout col = lane&15, row = (lane>>4)*4 + j   [m89-verified]
#pragma unroll
    for (int i = 0; i < 2; ++i) {
#pragma unroll
        for (int jx = 0; jx < 4; ++jx) {
            const int mbase = m0 + wm * 32 + i * 16 + lg * 4;
            const int n = n0 + wn * 64 + jx * 16 + ls;
            if (mode == 3) {
#pragma unroll
                for (int j = 0; j < 4; ++j)
                    ((float*)outp)[(size_t)(mbase + j) * EMBED + n] = acc[i][jx][j] + bias[n];
            } else if (mode == 2) {
                // V^T [bh][d][s]: j-loop contiguous along s -> one 8B store
                const int b = mbase >> 11, s = mbase & 2047;
                const int h = n >> 6, d = n & 63;
                __bf16 t4[4];
#pragma unroll
                for (int j = 0; j < 4; ++j) t4[j] = (__bf16)(acc[i][jx][j] + bias[n]);
                *(uint2*)&((__bf16*)outp)[(((size_t)(b * NH + h) * DH + d) << 11) + s] = *(uint2*)t4;
            } else {
                const float sc2 = (mode == 0) ? QSCALE : 1.0f;
#pragma unroll
                for (int j = 0; j < 4; ++j) {
                    const int m = mbase + j;
                    const int b = m >> 11, s = m & 2047;
                    const int h = n >> 6, d = n & 63;
                    ((__bf16*)outp)[((((size_t)(b * NH + h) << 11) + s) * DH) + d] =
                        (__bf16)((acc[i][jx][j] + bias[n]) * sc2);
                }
            }
        }
    }
}

// ---------------------------------------------------------------------------
// MFMA causal flash attention — r16 skeleton + K-ONLY DEPTH-2 PREFETCH, 24 KB.
// r22 theory: per-tile 4500 cyc = 1800 busy + ~2700 exposed vmcnt (K and V
// waits ~1200+ each at depth-1 distance). r21 proved dual-buffering BOTH
// (32 KB) costs residency (4->3 blocks/CU, net loss). Compromise: K gets
// depth-2 (2 x 8KB buffers; K_{t+2} issued after QK^T's fence into the
// just-freed buffer -> ~2-tile wait distance, exposed ~0), V keeps the r16
// single-buffer schedule. LDS 24 KB targets the 16KB residency tier (~4/CU).
// vmcnt: K-wait = V_t + K_{t+1} younger -> (16), (8) on last tile;
//        V-wait = K_{t+1} + K_{t+2} younger -> (16)/(8)/(0) at tail.
// Prologue: K0, V0, K1 (24 loads). One wave/block, frozen-max softmax,
// swapped QK^T (S^T=K@Q^T), P->bf16 via v_cvt_pk_bf16_f32 +
// v_permlane32_swap_b32, XOR-swizzled LDS rows (pre-swizzled source).
// Grid = 32 bh x 64 q-tiles = 2048 blocks x 64 thr, heavy-first; same-bh
// blocks stride 32 -> same XCD.
// Q,K: [bh][s][d] bf16 (Q pre-scaled 0.125*log2e). Vt: [bh][d][s] bf16.
// ctx: bf16 [b*SEQ+s][h*64+d].
// ---------------------------------------------------------------------------
__global__ __launch_bounds__(64) void attn_mfma(
    const __bf16* __restrict__ Q, const __bf16* __restrict__ K,
    const __bf16* __restrict__ Vt, __bf16* __restrict__ ctx)
{
    __shared__ __bf16 lds[12288];        // bytes: K buf0 [0,8K), K buf1 [8K,16K), V [16K,24K)

    const int lane = threadIdx.x & 63;
    const int col  = lane & 31;          // q column / fragment row index
    const int hi   = lane >> 5;
    const int bh   = blockIdx.x & 31;    // same-bh blocks stride 32 -> same XCD
    const int qt32 = 63 - (blockIdx.x >> 5);  // reversed: long blocks first
    const int qlo  = qt32 * 32;          // this block's 32 q rows
    const int b = bh >> 4, h = bh & 15;

    const __bf16* __restrict__ Qb = Q + ((size_t)bh << 11) * DH;
    const char* __restrict__ Kg = (const char*)(K  + ((size_t)bh << 11) * DH);
    const char* __restrict__ Vg = (const char*)(Vt + ((size_t)bh << 11) * DH);

    char* const ldsK0 = (char*)&lds[0];
    char* const ldsV  = ldsK0 + 16384;

    // staging (64 lanes): instr i covers tile bytes [i*1024 + lane*16);
    // row = i*8 + (lane>>3); col-byte = (lane&7)*16; row&7 = lane>>3
    const int srow = lane >> 3;                              // 0..7
    const int sswz = ((lane & 7) * 16) ^ (srow << 4);        // pre-swizzled source col
    const int swz  = (col & 7) << 4;

    // Q B-frags (col = q, k-dim = d)
    bf16x8 qf[4];
#pragma unroll
    for (int c = 0; c < 4; ++c)
        qf[c] = *(const bf16x8*)&Qb[(size_t)(qlo + col) * DH + c * 16 + hi * 8];

    const int nt = (qt32 + 2) >> 1;      // 64-key tiles covering keys 0..qlo+31

    // prologue: K0, V0, K1 (issue order matters for vmcnt counting)
#pragma unroll
    for (int i = 0; i < 8; ++i)
        gload16(Kg + (size_t)(i * 8 + srow) * 128 + sswz, ldsK0 + i * 1024 + lane * 16);
#pragma unroll
    for (int i = 0; i < 8; ++i)
        gload16(Vg + (size_t)(i * 8 + srow) * 4096 + sswz, ldsV + i * 1024 + lane * 16);
    if (nt > 1) {
#pragma unroll
        for (int i = 0; i < 8; ++i)
            gload16(Kg + (size_t)(64 + i * 8 + srow) * 128 + sswz,
                    ldsK0 + 8192 + i * 1024 + lane * 16);
    }

    f32x16 oT0 = {}, oT1 = {};           // O^T[d][q], d-halves 0-31 / 32-63
    float mrun = 0.f, lrun = 0.f;        // mrun set on tile 0, then FROZEN

    for (int t = 0; t < nt; ++t) {
        const int k0 = t * 64;
        const char* ldsK = ldsK0 + (t & 1) * 8192;
        const bool haveK1 = (t + 1 < nt);   // K_{t+1} staged (in flight or done)
        const bool stageK2 = (t + 2 < nt);  // will stage K_{t+2} this tile

        // ---- K_t ready. Younger: V_t (8) + K_{t+1} (8 if staged) ----
        if (haveK1) { asm volatile("s_waitcnt vmcnt(16)" ::: "memory"); }
        else        { asm volatile("s_waitcnt vmcnt(8)"  ::: "memory"); }

        // ---- K fragments for both 32-key subtiles (swizzled LDS read) ----
        bf16x8 kfa[4], kfb[4];
#pragma unroll
        for (int c = 0; c < 4; ++c) {
            kfa[c] = *(const bf16x8*)(ldsK + (     col) * 128 + ((c * 32 + hi * 16) ^ swz));
            kfb[c] = *(const bf16x8*)(ldsK + (32 + col) * 128 + ((c * 32 + hi * 16) ^ swz));
        }

        // ---- QK^T: two independent S^T[32k][32q] chains ----
        __builtin_amdgcn_s_setprio(1);
        f32x16 sta = {}, stb = {};
#pragma unroll
        for (int c = 0; c < 4; ++c) {
            sta = __builtin_amdgcn_mfma_f32_32x32x16_bf16(kfa[c], qf[c], sta, 0, 0, 0);
            stb = __builtin_amdgcn_mfma_f32_32x32x16_bf16(kfb[c], qf[c], stb, 0, 0, 0);
        }
        __builtin_amdgcn_s_setprio(0);

        // ---- K buf (t&1) dead: fence ds_reads, stage K_{t+2} into it ----
        asm volatile("s_waitcnt lgkmcnt(0)" ::: "memory");
        __builtin_amdgcn_sched_barrier(0);
        if (stageK2) {
            const int kbn = (t + 2) * 64;
#pragma unroll
            for (int i = 0; i < 8; ++i)
                gload16(Kg + (size_t)(kbn + i * 8 + srow) * 128 + sswz,
                        ldsK0 + (t & 1) * 8192 + i * 1024 + lane * 16);
        }

        // ---- causal mask (diagonal-crossing tiles only) ----
        if (k0 + 63 > qlo) {
#pragma unroll
            for (int r = 0; r < 16; ++r) {
                const int krel = (r & 3) + 8 * (r >> 2) + 4 * hi;
                if (k0 + krel > qlo + col)      sta[r] = -INFINITY;
                if (k0 + 32 + krel > qlo + col) stb[r] = -INFINITY;
            }
        }

        // ---- frozen-max softmax: fmax tree ONLY on tile 0 ----
        if (t == 0) {
            float ta = fmaxf(fmaxf(fmaxf(sta[0], sta[1]), fmaxf(sta[2], sta[3])),
                             fmaxf(fmaxf(sta[4], sta[5]), fmaxf(sta[6], sta[7])));
            float tb = fmaxf(fmaxf(fmaxf(sta[8], sta[9]),  fmaxf(sta[10], sta[11])),
                             fmaxf(fmaxf(sta[12], sta[13]), fmaxf(sta[14], sta[15])));
            float tc = fmaxf(fmaxf(fmaxf(stb[0], stb[1]), fmaxf(stb[2], stb[3])),
                             fmaxf(fmaxf(stb[4], stb[5]), fmaxf(stb[6], stb[7])));
            float td = fmaxf(fmaxf(fmaxf(stb[8], stb[9]),  fmaxf(stb[10], stb[11])),
                             fmaxf(fmaxf(stb[12], stb[13]), fmaxf(stb[14], stb[15])));
            float tmax = fmaxf(fmaxf(ta, tb), fmaxf(tc, td));
            tmax = fmaxf(tmax, __shfl_xor(tmax, 32));
            mrun = tmax;                 // finite: every q-row has >=1 unmasked key
        }

        float pa[16], pb[16];
#pragma unroll
        for (int r = 0; r < 16; ++r) { pa[r] = exp2f(sta[r] - mrun); pb[r] = exp2f(stb[r] - mrun); }
        float psa = (((pa[0] + pa[1]) + (pa[2] + pa[3])) + ((pa[4] + pa[5]) + (pa[6] + pa[7])))
                  + (((pa[8] + pa[9]) + (pa[10] + pa[11])) + ((pa[12] + pa[13]) + (pa[14] + pa[15])));
        float psb = (((pb[0] + pb[1]) + (pb[2] + pb[3])) + ((pb[4] + pb[5]) + (pb[6] + pb[7])))
                  + (((pb[8] + pb[9]) + (pb[10] + pb[11])) + ((pb[12] + pb[13]) + (pb[14] + pb[15])));
        float psum = psa + psb;
        psum += __shfl_xor(psum, 32);
        lrun += psum;

        // ---- pack P -> bf16 B-frags (cvt_pk + permlane32_swap), per subtile ----
        u32 wa[8], wb[8];
#pragma unroll
        for (int i = 0; i < 8; ++i) {
            u32 r1, r2;
            asm("v_cvt_pk_bf16_f32 %0, %1, %2" : "=v"(r1) : "v"(pa[2 * i]), "v"(pa[2 * i + 1]));
            asm("v_cvt_pk_bf16_f32 %0, %1, %2" : "=v"(r2) : "v"(pb[2 * i]), "v"(pb[2 * i + 1]));
            wa[i] = r1; wb[i] = r2;
        }
        asm("v_permlane32_swap_b32 %0, %1" : "+v"(wa[0]), "+v"(wa[2]));
        asm("v_permlane32_swap_b32 %0, %1" : "+v"(wa[1]), "+v"(wa[3]));
        asm("v_permlane32_swap_b32 %0, %1" : "+v"(wa[4]), "+v"(wa[6]));
        asm("v_permlane32_swap_b32 %0, %1" : "+v"(wa[5]), "+v"(wa[7]));
        asm("v_permlane32_swap_b32 %0, %1" : "+v"(wb[0]), "+v"(wb[2]));
        asm("v_permlane32_swap_b32 %0, %1" : "+v"(wb[1]), "+v"(wb[3]));
        asm("v_permlane32_swap_b32 %0, %1" : "+v"(wb[4]), "+v"(wb[6]));
        asm("v_permlane32_swap_b32 %0, %1" : "+v"(wb[5]), "+v"(wb[7]));

        union { u32 u4[4]; bf16x8 v; } cA0, cA1, cB0, cB1;
        cA0.u4[0] = wa[0]; cA0.u4[1] = wa[1]; cA0.u4[2] = wa[2]; cA0.u4[3] = wa[3];
        cA1.u4[0] = wa[4]; cA1.u4[1] = wa[5]; cA1.u4[2] = wa[6]; cA1.u4[3] = wa[7];
        cB0.u4[0] = wb[0]; cB0.u4[1] = wb[1]; cB0.u4[2] = wb[2]; cB0.u4[3] = wb[3];
        cB1.u4[0] = wb[4]; cB1.u4[1] = wb[5]; cB1.u4[2] = wb[6]; cB1.u4[3] = wb[7];

        // ---- V_t ready. Younger: K_{t+1} (8 if staged) + K_{t+2} (8 if staged) ----
        if (stageK2)      { asm volatile("s_waitcnt vmcnt(16)" ::: "memory"); }
        else if (haveK1)  { asm volatile("s_waitcnt vmcnt(8)"  ::: "memory"); }
        else              { asm volatile("s_waitcnt vmcnt(0)"  ::: "memory"); }

        // ---- PV from LDS V^T (swizzled read): O^T += V^T[d][k] P^T[k][q] ----
        __builtin_amdgcn_s_setprio(1);
#pragma unroll
        for (int dh = 0; dh < 2; ++dh) {
            bf16x8 v0 = *(const bf16x8*)(ldsV + (dh * 32 + col) * 128 + ((0  + hi * 16) ^ swz));
            bf16x8 v1 = *(const bf16x8*)(ldsV + (dh * 32 + col) * 128 + ((32 + hi * 16) ^ swz));
            bf16x8 v2 = *(const bf16x8*)(ldsV + (dh * 32 + col) * 128 + ((64 + hi * 16) ^ swz));
            bf16x8 v3 = *(const bf16x8*)(ldsV + (dh * 32 + col) * 128 + ((96 + hi * 16) ^ swz));
            f32x16& o = dh ? oT1 : oT0;
            o = __builtin_amdgcn_mfma_f32_32x32x16_bf16(v0, cA0.v, o, 0, 0, 0);
            o = __builtin_amdgcn_mfma_f32_32x32x16_bf16(v1, cA1.v, o, 0, 0, 0);
            o = __builtin_amdgcn_mfma_f32_32x32x16_bf16(v2, cB0.v, o, 0, 0, 0);
            o = __builtin_amdgcn_mfma_f32_32x32x16_bf16(v3, cB1.v, o, 0, 0, 0);
        }
        __builtin_amdgcn_s_setprio(0);

        // ---- V-buf dead: fence ds_reads, stage V_{t+1} ----
        asm volatile("s_waitcnt lgkmcnt(0)" ::: "memory");
        __builtin_amdgcn_sched_barrier(0);
        if (haveK1) {
            const int kbn = (t + 1) * 64;
#pragma unroll
            for (int i = 0; i < 8; ++i)
                gload16(Vg + (size_t)(i * 8 + srow) * 4096 + (size_t)kbn * 2 + sswz,
                        ldsV + i * 1024 + lane * 16);
        }
    }

    // ---- epilogue: O[q][d] = O^T/l -> ctx[token][h*64+d], 8B packed stores ----
    const float inv = 1.0f / lrun;
    const size_t base = ((size_t)(b * SEQ + qlo + col)) * DINNER + h * 64;
#pragma unroll
    for (int g = 0; g < 4; ++g) {
        __bf16 t4[4];
#pragma unroll
        for (int j = 0; j < 4; ++j) t4[j] = (__bf16)(oT0[4 * g + j] * inv);
        *(uint2*)&ctx[base + 8 * g + 4 * hi] = *(uint2*)t4;
#pragma unroll
        for (int j = 0; j < 4; ++j) t4[j] = (__bf16)(oT1[4 * g + j] * inv);
        *(uint2*)&ctx[base + 32 + 8 * g + 4 * hi] = *(uint2*)t4;
    }
}

// ---------------------------------------------------------------------------
extern "C" void kernel_launch(void* const* d_in, const int* in_sizes, int n_in,
                              void* d_out, int out_size, void* d_ws, size_t ws_size,
                              hipStream_t stream)
{
    const float* X  = (const float*)d_in[0];
    const float* Wq = (const float*)d_in[1];
    const float* bq = (const float*)d_in[2];
    const float* Wk = (const float*)d_in[3];
    const float* bk = (const float*)d_in[4];
    const float* Wv = (const float*)d_in[5];
    const float* bv = (const float*)d_in[6];
    const float* Wo = (const float*)d_in[7];
    const float* bo = (const float*)d_in[8];
    float* out = (float*)d_out;

    // bf16 workspace layout (element offsets, 1 Mi = 1048576)
    __bf16* ws  = (__bf16*)d_ws;
    const size_t MI = 1048576;
    __bf16* Xb   = ws;               // 4 Mi  [4096][1024]
    __bf16* Wtq  = ws + 4  * MI;     // 1 Mi  [1024 n][1024 k]
    __bf16* Wtk  = ws + 5  * MI;
    __bf16* Wtv  = ws + 6  * MI;
    __bf16* Wto  = ws + 7  * MI;
    __bf16* Qb   = ws + 8  * MI;     // 4 Mi  [bh][s][d], pre-scaled 0.125*log2e
    __bf16* Kb   = ws + 12 * MI;     // 4 Mi  [bh][s][d]
    __bf16* Vtb  = ws + 16 * MI;     // 4 Mi  [bh][d][s]
    __bf16* ctxb = ws + 20 * MI;     // 4 Mi  [tok][h*64+d]

    // 1) convert input + 4 weight transposes
    cvt_bf16<<<dim3(MTOK * EMBED / 1024), dim3(256), 0, stream>>>(X, Xb, MTOK * EMBED);
    tconv4<<<dim3(32, 32, 4), dim3(256), 0, stream>>>(Wq, Wk, Wv, Wo, Wtq, Wtk, Wtv, Wto);

    // 2) fused QKV projection: 128^2 tile, 8 waves -> 768 blocks x 512 thr
    {
        dim3 grid(DINNER / 128, MTOK / 128, 3), blk(512);
        gemm128<<<grid, blk, 0, stream>>>(Xb, Wtq, Wtk, Wtv, bq, bk, bv,
                                          Qb, Kb, Vtb, EMBED, 0);
    }

    // 3) causal flash attention (K depth-2 / V depth-1, 24 KB, frozen-max)
    {
        dim3 grid(32 * (SEQ / 32)), blk(64);
        attn_mfma<<<grid, blk, 0, stream>>>(Qb, Kb, Vtb, ctxb);
    }

    // 4) output projection -> fp32 d_out: 128^2 tile, 8 waves -> 256 blocks x 512 thr
    {
        dim3 grid(EMBED / 128, MTOK / 128, 1), blk(512);
        gemm128<<<grid, blk, 0, stream>>>(ctxb, Wto, Wto, Wto, bo, bo, bo,
                                          out, out, out, DINNER, 1);
    }
}